// Round 1
// baseline (561.648 us; speedup 1.0000x reference)
//
#include <hip/hip_runtime.h>
#include <hip/hip_bf16.h>

// GlobalSLC: out = out_s + out_d
//   static : y1 = ws@x; y2 = 2ws@y1 - x; y3 = 2ws@y2 - y1   (3 big HBM-bound GEMMs)
//   dynamic: wd = xp x^T (never materialized); collapses to 32x32 coefficient algebra:
//            G = x^T x, W = G wp, H1 = W G, H2 = 2 W H1 - G
//   out = x@(2ts0 - td2) + xp@(G td1 + 2 H1 td2 + (2H2 - G) td3) + y1@ts1 + y2@ts2 + y3@ts3

typedef __attribute__((ext_vector_type(8))) short short8;
typedef __attribute__((ext_vector_type(4))) float floatx4;

__device__ inline short f2bf(float f) {
    union { float f; unsigned u; } v; v.f = f;
    unsigned r = v.u + 0x7FFFu + ((v.u >> 16) & 1u);   // RNE
    return (short)(r >> 16);
}

// ---------------- small kernels ----------------

// xp[n][c] = sum_a x[n][a] * wp[a][c]
__global__ void k_xp(const float* __restrict__ x, const float* __restrict__ wp,
                     float* __restrict__ xp) {
    __shared__ float swp[1024];
    int t = threadIdx.x;
    for (int i = t; i < 1024; i += 256) swp[i] = wp[i];
    __syncthreads();
    int g = blockIdx.x * 256 + t;
    int n = g >> 5, c = g & 31;
    const float* xr = x + n * 32;
    float s = 0.f;
#pragma unroll
    for (int a = 0; a < 32; ++a) s += xr[a] * swp[a * 32 + c];
    xp[g] = s;
}

// G[a][b] += sum over 256-row chunk of x[n][a]*x[n][b]   (G pre-zeroed)
__global__ void k_gram(const float* __restrict__ x, float* __restrict__ G) {
    int t = threadIdx.x;                 // 1024 threads: (a,b)
    int a = t >> 5, b = t & 31;
    int n0 = blockIdx.x * 256;
    float s = 0.f;
    for (int n = n0; n < n0 + 256; ++n) s += x[n * 32 + a] * x[n * 32 + b];
    atomicAdd(&G[t], s);
}

// 32x32 coefficient algebra (single block, 1024 threads)
__global__ void k_coef(const float* __restrict__ G_in, const float* __restrict__ wp,
                       const float* __restrict__ ts, const float* __restrict__ td,
                       float* __restrict__ Cx, float* __restrict__ Cxp) {
    __shared__ float G[1024], W[1024], H1[1024], H2[1024];
    __shared__ float swp[1024], td1[1024], td2[1024], td3[1024], ts0[1024];
    int t = threadIdx.x;
    int a = t >> 5, b = t & 31;
    G[t] = G_in[t]; swp[t] = wp[t]; ts0[t] = ts[t];
    td1[t] = td[1024 + t]; td2[t] = td[2048 + t]; td3[t] = td[3072 + t];
    __syncthreads();
    float s = 0.f;
    for (int c = 0; c < 32; ++c) s += G[a * 32 + c] * swp[c * 32 + b];
    W[t] = s; __syncthreads();
    s = 0.f;
    for (int c = 0; c < 32; ++c) s += W[a * 32 + c] * G[c * 32 + b];
    H1[t] = s; __syncthreads();
    s = 0.f;
    for (int c = 0; c < 32; ++c) s += W[a * 32 + c] * H1[c * 32 + b];
    H2[t] = 2.f * s - G[t]; __syncthreads();
    s = 0.f;
    for (int c = 0; c < 32; ++c)
        s += G[a * 32 + c] * td1[c * 32 + b]
           + 2.f * H1[a * 32 + c] * td2[c * 32 + b]
           + (2.f * H2[a * 32 + c] - G[a * 32 + c]) * td3[c * 32 + b];
    Cxp[t] = s;
    Cx[t] = 2.f * ts0[t] - td2[t];
}

// Vt[c][k] = bf16(V[k][c])   (transposed bf16 copy of the skinny operand)
__global__ void k_vt(const float* __restrict__ V, unsigned short* __restrict__ Vt) {
    int g = blockIdx.x * 256 + threadIdx.x;   // 0..262143
    int c = g >> 13;                          // /8192
    int k = g & 8191;
    Vt[g] = (unsigned short)f2bf(V[k * 32 + c]);
}

__global__ void k_neg(const float* __restrict__ src, float* __restrict__ dst) {
    int g = blockIdx.x * 256 + threadIdx.x;
    dst[g] = -src[g];
}

// ---------------- big GEMM: Y += alpha * A(8192x8192 fp32) @ V(8192x32) ----------------
// grid (128, 8): 64-row tiles x split-K(1024 each). 256 threads = 4 waves, wave per 16 rows.
// A staged fp32 -> LDS via global_load_lds(16B) with 16B-chunk XOR swizzle, cvt to bf16 in-reg,
// mfma_f32_16x16x32_bf16; B frags read straight from bf16 Vt (L2-resident).
__global__ __launch_bounds__(256) void k_gemm(const float* __restrict__ A,
                                              const unsigned short* __restrict__ Vt,
                                              float* __restrict__ Y, float alpha) {
    __shared__ float sm[64 * 64];             // 16 KB, one 64x64 fp32 tile (swizzled chunks)
    const int t = threadIdx.x;
    const int lane = t & 63;
    const int wv = t >> 6;
    const int l15 = lane & 15;
    const int l4 = lane >> 4;
    const int m0 = blockIdx.x * 64;
    const int k0 = blockIdx.y * 1024;

    floatx4 acc0 = {0.f, 0.f, 0.f, 0.f};
    floatx4 acc1 = {0.f, 0.f, 0.f, 0.f};

    for (int kt = 0; kt < 1024; kt += 64) {
        __syncthreads();                      // previous tile fully consumed
#pragma unroll
        for (int i = 0; i < 4; ++i) {
            int r = i * 16 + (t >> 4);        // LDS row 0..63
            int j = t & 15;                   // LDS 16B-chunk slot 0..15
            int cch = j ^ (r & 15);           // swizzle: slot j holds global chunk j^r
            const float* gsrc = A + (size_t)(m0 + r) * 8192 + (k0 + kt) + cch * 4;
            float* ldst = &sm[(i * 16 + wv * 4) * 64];   // lane0 base (wave-uniform)
            __builtin_amdgcn_global_load_lds(
                (const __attribute__((address_space(1))) unsigned int*)gsrc,
                (__attribute__((address_space(3))) unsigned int*)ldst,
                16, 0, 0);
        }
        __syncthreads();                      // drains vmcnt before use
#pragma unroll
        for (int kh = 0; kh < 2; ++kh) {
            int rl = wv * 16 + l15;           // my A row in LDS
            int jb = kh * 8 + l4 * 2;         // wanted chunk (8 consecutive k = 2 chunks)
            floatx4 f0 = *(floatx4*)&sm[rl * 64 + ((jb    ) ^ l15) * 4];
            floatx4 f1 = *(floatx4*)&sm[rl * 64 + ((jb + 1) ^ l15) * 4];
            short8 av;
            av[0] = f2bf(f0.x); av[1] = f2bf(f0.y); av[2] = f2bf(f0.z); av[3] = f2bf(f0.w);
            av[4] = f2bf(f1.x); av[5] = f2bf(f1.y); av[6] = f2bf(f1.z); av[7] = f2bf(f1.w);
            int kk = k0 + kt + kh * 32 + l4 * 8;
            short8 b0 = *(const short8*)(Vt + (size_t)l15 * 8192 + kk);
            short8 b1 = *(const short8*)(Vt + (size_t)(16 + l15) * 8192 + kk);
            acc0 = __builtin_amdgcn_mfma_f32_16x16x32_bf16(av, b0, acc0, 0, 0, 0);
            acc1 = __builtin_amdgcn_mfma_f32_16x16x32_bf16(av, b1, acc1, 0, 0, 0);
        }
    }
    // epilogue: C/D layout col=lane&15, row=(lane>>4)*4+i ; split-K -> atomicAdd
    int row0 = m0 + wv * 16 + l4 * 4;
#pragma unroll
    for (int i = 0; i < 4; ++i) {
        atomicAdd(&Y[(size_t)(row0 + i) * 32 + l15], alpha * acc0[i]);
        atomicAdd(&Y[(size_t)(row0 + i) * 32 + 16 + l15], alpha * acc1[i]);
    }
}

// out = x@Cx + xp@Cxp + y1@ts1 + y2@ts2 + y3@ts3
__global__ void k_final(const float* __restrict__ x, const float* __restrict__ xp,
                        const float* __restrict__ y1, const float* __restrict__ y2,
                        const float* __restrict__ y3, const float* __restrict__ Cx,
                        const float* __restrict__ Cxp, const float* __restrict__ ts,
                        float* __restrict__ out) {
    __shared__ float m0[1024], m1[1024], m2[1024], m3[1024], m4[1024];
    int t = threadIdx.x;
    for (int i = t; i < 1024; i += 256) {
        m0[i] = Cx[i]; m1[i] = Cxp[i];
        m2[i] = ts[1024 + i]; m3[i] = ts[2048 + i]; m4[i] = ts[3072 + i];
    }
    __syncthreads();
    int g = blockIdx.x * 256 + t;
    int n = g >> 5, c = g & 31;
    const float* xr  = x  + n * 32;
    const float* xpr = xp + n * 32;
    const float* y1r = y1 + n * 32;
    const float* y2r = y2 + n * 32;
    const float* y3r = y3 + n * 32;
    float s = 0.f;
#pragma unroll
    for (int a = 0; a < 32; ++a) {
        s += xr[a]  * m0[a * 32 + c]
           + xpr[a] * m1[a * 32 + c]
           + y1r[a] * m2[a * 32 + c]
           + y2r[a] * m3[a * 32 + c]
           + y3r[a] * m4[a * 32 + c];
    }
    out[g] = s;
}

extern "C" void kernel_launch(void* const* d_in, const int* in_sizes, int n_in,
                              void* d_out, int out_size, void* d_ws, size_t ws_size,
                              hipStream_t stream) {
    const float* x  = (const float*)d_in[0];   // 8192 x 32
    const float* ws = (const float*)d_in[1];   // 8192 x 8192
    const float* wp = (const float*)d_in[2];   // 32 x 32
    const float* ts = (const float*)d_in[3];   // 4 x 32 x 32
    const float* td = (const float*)d_in[4];   // 4 x 32 x 32
    float* out = (float*)d_out;

    float* xp  = (float*)d_ws;                 // 262144
    float* y1  = xp + 262144;
    float* y2  = y1 + 262144;
    float* y3  = y2 + 262144;
    float* G   = y3 + 262144;                  // 1024
    float* Cx  = G + 1024;                     // 1024
    float* Cxp = Cx + 1024;                    // 1024
    unsigned short* Vt = (unsigned short*)(Cxp + 1024);   // 32 x 8192 bf16 (512 KB)

    // dynamic-branch coefficient algebra
    hipMemsetAsync(G, 0, 1024 * sizeof(float), stream);
    k_xp<<<1024, 256, 0, stream>>>(x, wp, xp);
    k_gram<<<32, 1024, 0, stream>>>(x, G);
    k_coef<<<1, 1024, 0, stream>>>(G, wp, ts, td, Cx, Cxp);

    dim3 gg(128, 8);
    // pass 1: y1 = ws @ x
    k_vt<<<1024, 256, 0, stream>>>(x, Vt);
    hipMemsetAsync(y1, 0, 262144 * sizeof(float), stream);
    k_gemm<<<gg, 256, 0, stream>>>(ws, Vt, y1, 1.0f);
    // pass 2: y2 = 2 ws @ y1 - x
    k_vt<<<1024, 256, 0, stream>>>(y1, Vt);
    k_neg<<<1024, 256, 0, stream>>>(x, y2);
    k_gemm<<<gg, 256, 0, stream>>>(ws, Vt, y2, 2.0f);
    // pass 3: y3 = 2 ws @ y2 - y1
    k_vt<<<1024, 256, 0, stream>>>(y2, Vt);
    k_neg<<<1024, 256, 0, stream>>>(y1, y3);
    k_gemm<<<gg, 256, 0, stream>>>(ws, Vt, y3, 2.0f);

    k_final<<<1024, 256, 0, stream>>>(x, xp, y1, y2, y3, Cx, Cxp, ts, out);
}